// Round 2
// baseline (1586.171 us; speedup 1.0000x reference)
//
#include <hip/hip_runtime.h>

#define NN 20000
#define NE 100000
#define EPAD 100096   // NE padded up to multiple of 128
#define INF 16
#define HID 64

typedef __attribute__((ext_vector_type(8))) short short8;
typedef __attribute__((ext_vector_type(4))) float f32x4;

// scal layout (float indices)
#define QS   0    // q_star[128]
#define SHL  128  // hl[64]
#define SCL  192  // cl[64]
#define SQ   256  // q[64]
#define SMAX 320  // maxv[3]
#define SSW  324  // sumw[3]
#define SRD  384  // readout_unnorm[3][64]

__device__ inline unsigned short f2b(float f) {
    union { float f; unsigned u; } c; c.f = f;
    unsigned u = c.u;
    unsigned r = u + 0x7fffu + ((u >> 16) & 1u);
    return (unsigned short)(r >> 16);
}
__device__ inline float sigm(float x) { return 1.f / (1.f + expf(-x)); }

__global__ void k_sentinel(float* out) { out[0] = 12345.0f; }

// ---------------- lin0 + relu ----------------
__global__ __launch_bounds__(256) void k_lin0(const float* __restrict__ nfeat,
        const float* __restrict__ w, const float* __restrict__ b,
        float* __restrict__ X) {
    int t = blockIdx.x * 256 + threadIdx.x;   // N*64 threads
    int n = t >> 6, o = t & 63;
    float acc = b[o];
    #pragma unroll
    for (int i = 0; i < INF; ++i) acc += nfeat[n * INF + i] * w[i * HID + o];
    X[t] = fmaxf(acc, 0.f);
}

// ---------------- edge MLP layer 1 + relu -> bf16 ----------------
__global__ __launch_bounds__(256) void k_e1(const float* __restrict__ efeat,
        const float* __restrict__ w, const float* __restrict__ b,
        unsigned short* __restrict__ h1b) {
    int t = blockIdx.x * 256 + threadIdx.x;   // E*128 threads
    int e = t >> 7, k = t & 127;
    float acc = b[k];
    #pragma unroll
    for (int i = 0; i < 5; ++i) acc += efeat[e * 5 + i] * w[i * 128 + k];
    h1b[t] = f2b(fmaxf(acc, 0.f));
}

// ---------------- in-degree ----------------
__global__ void k_deg(const int* __restrict__ dst, float* __restrict__ deg, int E) {
    int e = blockIdx.x * blockDim.x + threadIdx.x;
    if (e < E) atomicAdd(&deg[dst[e]], 1.0f);
}

// ---------------- transpose e2_w [128,4096] f32 -> w2t [4096,128] bf16 ----------------
__global__ __launch_bounds__(256) void k_tr(const float* __restrict__ w2,
        unsigned short* __restrict__ w2t) {
    __shared__ float t[128][65];
    int tid = threadIdx.x;
    int og0 = blockIdx.x * 64;
    for (int v = tid; v < 2048; v += 256) {      // 128 k-rows x 16 float4
        int k = v >> 4, c4 = (v & 15) << 2;
        float4 val = *reinterpret_cast<const float4*>(&w2[(size_t)k * 4096 + og0 + c4]);
        t[k][c4 + 0] = val.x; t[k][c4 + 1] = val.y;
        t[k][c4 + 2] = val.z; t[k][c4 + 3] = val.w;
    }
    __syncthreads();
    int ogl = tid >> 2;                // 0..63
    int k0 = (tid & 3) * 32;           // 32 k per thread
    unsigned short buf[32];
    #pragma unroll
    for (int j = 0; j < 32; ++j) buf[j] = f2b(t[k0 + j][ogl]);
    size_t base = (size_t)(og0 + ogl) * 128 + k0;
    #pragma unroll
    for (int q = 0; q < 8; ++q) {
        ushort4 uv;
        uv.x = buf[q * 4 + 0]; uv.y = buf[q * 4 + 1];
        uv.z = buf[q * 4 + 2]; uv.w = buf[q * 4 + 3];
        *reinterpret_cast<ushort4*>(&w2t[base + q * 4]) = uv;
    }
}

// ---------------- fused msg: msg^T[o,e] = sum_i x[e,i] * (W2T_i @ H1^T) ----------------
// Block: 64 o x 128 e, 4 waves (2 o-halves x 2 e-halves), MFMA 16x16x32 bf16.
// A-frag = w2t rows (o,k); B-frag = h1 rows (e,k) as H^T[k,e]; D[o,e].
__global__ __launch_bounds__(256) void k_msg(const float* __restrict__ X,
        const unsigned short* __restrict__ h1b, const unsigned short* __restrict__ w2t,
        const int* __restrict__ src, const int* __restrict__ dst,
        float* __restrict__ agg) {
    __shared__ float xe[128][65];
    const int tid = threadIdx.x;
    const int e0 = blockIdx.x * 128;
    for (int v = tid; v < 128 * 16; v += 256) {
        int row = v >> 4, c4 = (v & 15) << 2;
        int ee = e0 + row;
        float4 val = make_float4(0.f, 0.f, 0.f, 0.f);
        if (ee < NE)
            val = *reinterpret_cast<const float4*>(&X[(size_t)src[ee] * 64 + c4]);
        xe[row][c4 + 0] = val.x; xe[row][c4 + 1] = val.y;
        xe[row][c4 + 2] = val.z; xe[row][c4 + 3] = val.w;
    }
    __syncthreads();
    const int w = tid >> 6, l = tid & 63;
    const int wo  = (w >> 1) * 32;   // o base (0 or 32)
    const int weh = (w & 1) * 64;    // e base within block (0 or 64)
    const int l15 = l & 15, lh = l >> 4;

    // B fragments (h1, i-invariant): bfr[ef][ks], lane col e = weh+ef*16+l15
    short8 bfr[4][4];
    #pragma unroll
    for (int ef = 0; ef < 4; ++ef) {
        const unsigned short* hp = &h1b[(size_t)(e0 + weh + ef * 16 + l15) * 128 + lh * 8];
        #pragma unroll
        for (int ks = 0; ks < 4; ++ks)
            bfr[ef][ks] = *reinterpret_cast<const short8*>(hp + ks * 32);
    }

    f32x4 acc[2][4];
    #pragma unroll
    for (int of = 0; of < 2; ++of)
        #pragma unroll
        for (int ef = 0; ef < 4; ++ef) acc[of][ef] = f32x4{0.f, 0.f, 0.f, 0.f};
    const f32x4 zero = f32x4{0.f, 0.f, 0.f, 0.f};

    short8 a_cur[2][4], a_nxt[2][4];
    #pragma unroll
    for (int of = 0; of < 2; ++of) {
        const unsigned short* ap = &w2t[(size_t)(wo + of * 16 + l15) * 128 + lh * 8];
        #pragma unroll
        for (int ks = 0; ks < 4; ++ks)
            a_cur[of][ks] = *reinterpret_cast<const short8*>(ap + ks * 32);
    }

    for (int i = 0; i < 64; ++i) {
        if (i < 63) {
            #pragma unroll
            for (int of = 0; of < 2; ++of) {
                const unsigned short* ap =
                    &w2t[(size_t)((i + 1) * 64 + wo + of * 16 + l15) * 128 + lh * 8];
                #pragma unroll
                for (int ks = 0; ks < 4; ++ks)
                    a_nxt[of][ks] = *reinterpret_cast<const short8*>(ap + ks * 32);
            }
        }
        f32x4 tmp[2][4];
        #pragma unroll
        for (int of = 0; of < 2; ++of)
            #pragma unroll
            for (int ef = 0; ef < 4; ++ef) {
                tmp[of][ef] = __builtin_amdgcn_mfma_f32_16x16x32_bf16(a_cur[of][0], bfr[ef][0], zero, 0, 0, 0);
                tmp[of][ef] = __builtin_amdgcn_mfma_f32_16x16x32_bf16(a_cur[of][1], bfr[ef][1], tmp[of][ef], 0, 0, 0);
                tmp[of][ef] = __builtin_amdgcn_mfma_f32_16x16x32_bf16(a_cur[of][2], bfr[ef][2], tmp[of][ef], 0, 0, 0);
                tmp[of][ef] = __builtin_amdgcn_mfma_f32_16x16x32_bf16(a_cur[of][3], bfr[ef][3], tmp[of][ef], 0, 0, 0);
            }
        #pragma unroll
        for (int ef = 0; ef < 4; ++ef) {
            const float xv = xe[weh + ef * 16 + l15][i];
            #pragma unroll
            for (int of = 0; of < 2; ++of)
                #pragma unroll
                for (int r = 0; r < 4; ++r)
                    acc[of][ef][r] += xv * tmp[of][ef][r];
        }
        #pragma unroll
        for (int of = 0; of < 2; ++of)
            #pragma unroll
            for (int ks = 0; ks < 4; ++ks) a_cur[of][ks] = a_nxt[of][ks];
    }

    #pragma unroll
    for (int ef = 0; ef < 4; ++ef) {
        const int e = e0 + weh + ef * 16 + l15;
        if (e < NE) {
            const int d = dst[e];
            float* ap = &agg[(size_t)d * 64 + wo];
            #pragma unroll
            for (int of = 0; of < 2; ++of)
                #pragma unroll
                for (int r = 0; r < 4; ++r)
                    atomicAdd(&ap[of * 16 + lh * 4 + r], acc[of][ef][r]);
        }
    }
}

// ---------------- NNConv bias+relu + GRU cell (in-place h update) ----------------
__global__ __launch_bounds__(256) void k_gru(const float* __restrict__ agg,
        const float* __restrict__ deg, const float* __restrict__ cbias,
        const float* __restrict__ wih, const float* __restrict__ whh,
        const float* __restrict__ bih, const float* __restrict__ bhh,
        float* __restrict__ X) {
    __shared__ float ms[4][68], hs[4][68];
    int tid = threadIdx.x;
    int sub = tid >> 6, l = tid & 63;
    int n = blockIdx.x * 4 + sub;
    float dv = fmaxf(deg[n], 1.f);
    float m = fmaxf(agg[(size_t)n * 64 + l] / dv + cbias[l], 0.f);
    float h = X[(size_t)n * 64 + l];
    ms[sub][l] = m; hs[sub][l] = h;
    __syncthreads();
    float gr = bih[l], gz = bih[64 + l], gn = bih[128 + l];
    float hr = bhh[l], hz = bhh[64 + l], hn = bhh[128 + l];
    #pragma unroll 8
    for (int i = 0; i < 64; ++i) {
        float mi = ms[sub][i], hi = hs[sub][i];
        gr += mi * wih[i * 192 + l];
        gz += mi * wih[i * 192 + 64 + l];
        gn += mi * wih[i * 192 + 128 + l];
        hr += hi * whh[i * 192 + l];
        hz += hi * whh[i * 192 + 64 + l];
        hn += hi * whh[i * 192 + 128 + l];
    }
    float r = sigm(gr + hr);
    float z = sigm(gz + hz);
    float nn2 = tanhf(gn + r * hn);
    X[(size_t)n * 64 + l] = (1.f - z) * nn2 + z * h;
}

// ---------------- Set2Set: LSTM cell (single block) ----------------
__global__ void k_lstm(const float* __restrict__ wih, const float* __restrict__ whh,
        const float* __restrict__ bih, const float* __restrict__ bhh,
        float* __restrict__ scal) {
    __shared__ float g[256];
    int t = threadIdx.x;
    float acc = bih[t] + bhh[t];
    for (int i = 0; i < 128; ++i) acc += scal[QS + i] * wih[i * 256 + t];
    for (int i = 0; i < 64; ++i)  acc += scal[SHL + i] * whh[i * 256 + t];
    g[t] = acc;
    __syncthreads();
    if (t < 64) {
        float ig = sigm(g[t]), fg = sigm(g[64 + t]);
        float gg = tanhf(g[128 + t]), og = sigm(g[192 + t]);
        float c = fg * scal[SCL + t] + ig * gg;
        float h = og * tanhf(c);
        scal[SCL + t] = c; scal[SHL + t] = h; scal[SQ + t] = h;
    }
}

// ---------------- e[n] = dot(X[n], q) ----------------
__global__ __launch_bounds__(256) void k_escore(const float* __restrict__ X,
        const float* __restrict__ scal, float* __restrict__ ev) {
    int tid = threadIdx.x;
    int w = tid >> 6, l = tid & 63;
    int n = blockIdx.x * 4 + w;
    float v = X[(size_t)n * 64 + l] * scal[SQ + l];
    #pragma unroll
    for (int off = 32; off; off >>= 1) v += __shfl_down(v, off, 64);
    if (l == 0) ev[n] = v;
}

// ---------------- softmax max (single block) ----------------
__global__ void k_max(const float* __restrict__ ev, float* __restrict__ scal, int it) {
    __shared__ float red[1024];
    int t = threadIdx.x;
    float m = -1e30f;
    for (int n = t; n < NN; n += 1024) m = fmaxf(m, ev[n]);
    red[t] = m;
    __syncthreads();
    for (int s2 = 512; s2; s2 >>= 1) {
        if (t < s2) red[t] = fmaxf(red[t], red[t + s2]);
        __syncthreads();
    }
    if (t == 0) scal[SMAX + it] = red[0];
}

// ---------------- weighted readout accumulation ----------------
__global__ __launch_bounds__(256) void k_wread(const float* __restrict__ X,
        const float* __restrict__ ev, float* __restrict__ scal, int it) {
    __shared__ float accs[4][68];
    __shared__ float sws[4];
    int tid = threadIdx.x;
    int w = tid >> 6, l = tid & 63;
    float maxv = scal[SMAX + it];
    int gw = blockIdx.x * 4 + w;      // 256 waves total
    float acc = 0.f, sw = 0.f;
    for (int n = gw; n < NN; n += 256) {
        float wt = expf(ev[n] - maxv);
        acc += wt * X[(size_t)n * 64 + l];
        sw += wt;
    }
    accs[w][l] = acc;
    if (l == 0) sws[w] = sw;
    __syncthreads();
    if (w == 0) {
        float a = accs[0][l] + accs[1][l] + accs[2][l] + accs[3][l];
        atomicAdd(&scal[SRD + it * 64 + l], a);
        if (l == 0) atomicAdd(&scal[SSW + it], sws[0] + sws[1] + sws[2] + sws[3]);
    }
}

// ---------------- q_star = [q, readout/sumw]; final write ----------------
__global__ void k_fin(float* __restrict__ scal, float* __restrict__ dq, int it) {
    int t = threadIdx.x;  // 128
    float v;
    if (t < 64) v = scal[SQ + t];
    else        v = scal[SRD + it * 64 + (t - 64)] / scal[SSW + it];
    scal[QS + t] = v;
    if (dq) dq[t] = v;
}

extern "C" void kernel_launch(void* const* d_in, const int* in_sizes, int n_in,
                              void* d_out, int out_size, void* d_ws, size_t ws_size,
                              hipStream_t stream) {
    const float* nfeat   = (const float*)d_in[0];
    const float* efeat   = (const float*)d_in[1];
    const int*   src     = (const int*)d_in[2];
    const int*   dst     = (const int*)d_in[3];
    const float* lin0_w  = (const float*)d_in[4];
    const float* lin0_b  = (const float*)d_in[5];
    const float* e1_w    = (const float*)d_in[6];
    const float* e1_b    = (const float*)d_in[7];
    const float* e2_w    = (const float*)d_in[8];
    // d_in[9] = e2_b: folded? NO — e2_b must be added to w_e. See below.
    const float* e2_b    = (const float*)d_in[9];
    const float* conv_b  = (const float*)d_in[10];
    const float* gwih    = (const float*)d_in[11];
    const float* gwhh    = (const float*)d_in[12];
    const float* gbih    = (const float*)d_in[13];
    const float* gbhh    = (const float*)d_in[14];
    const float* lwih    = (const float*)d_in[15];
    const float* lwhh    = (const float*)d_in[16];
    const float* lbih    = (const float*)d_in[17];
    const float* lbhh    = (const float*)d_in[18];

    const int N = NN, E = NE;

    // Workspace layout (bytes)
    size_t oX    = 0;                                    // N*64 f32
    size_t oAgg  = oX    + (size_t)N * 64 * 4;
    size_t oDeg  = oAgg  + (size_t)N * 64 * 4;
    size_t oEv   = oDeg  + (size_t)N * 4;
    size_t oScal = oEv   + (size_t)N * 4;
    size_t oH1   = oScal + 4096;                         // EPAD*128 bf16
    size_t oW2T  = oH1   + (size_t)EPAD * 128 * 2;       // 4096*128 bf16
    size_t needed = oW2T + (size_t)4096 * 128 * 2;

    float* outp = (float*)d_out;
    if (ws_size < needed) {
        k_sentinel<<<1, 1, 0, stream>>>(outp);
        return;
    }

    char* wsb = (char*)d_ws;
    float* X    = (float*)(wsb + oX);
    float* agg  = (float*)(wsb + oAgg);
    float* deg  = (float*)(wsb + oDeg);
    float* ev   = (float*)(wsb + oEv);
    float* scal = (float*)(wsb + oScal);
    unsigned short* h1b = (unsigned short*)(wsb + oH1);
    unsigned short* w2t = (unsigned short*)(wsb + oW2T);

    hipMemsetAsync(deg, 0, (size_t)N * 4, stream);
    hipMemsetAsync(scal, 0, 4096, stream);
    // zero h1 padding rows (edges E..EPAD) so garbage bf16 can't make NaN
    hipMemsetAsync(h1b + (size_t)E * 128, 0, (size_t)(EPAD - E) * 128 * 2, stream);

    k_lin0<<<(N * HID) / 256, 256, 0, stream>>>(nfeat, lin0_w, lin0_b, X);
    k_e1<<<(E * 128) / 256, 256, 0, stream>>>(efeat, e1_w, e1_b, h1b);
    k_deg<<<(E + 255) / 256, 256, 0, stream>>>(dst, deg, E);
    k_tr<<<64, 256, 0, stream>>>(e2_w, w2t);

    // NOTE on e2_b: w_e includes +e2_b[i*64+o]; its msg contribution is
    // Σ_i x[e,i]*e2_b[i*64+o]. Fold it in by appending a virtual h1 column?
    // Simpler: treat bias as extra K: we instead add it via an extra rank-1
    // pass in k_bias below (VALU, cheap).
    for (int r = 0; r < 3; ++r) {
        hipMemsetAsync(agg, 0, (size_t)N * 64 * 4, stream);
        k_msg<<<(E + 127) / 128, 256, 0, stream>>>(X, h1b, w2t, src, dst, agg);
        // bias contribution: msg_bias[e,o] = Σ_i x[e,i]*e2_b[i*64+o]
        // handled inside k_gru? No - needs per-edge x. Launch dedicated kernel:
        // (defined below main loop for clarity)
        extern __global__ void k_bias(const float*, const float*, const int*,
                                      const int*, float*);
        k_bias<<<(E + 15) / 16, 256, 0, stream>>>(X, e2_b, src, dst, agg);
        k_gru<<<N / 4, 256, 0, stream>>>(agg, deg, conv_b, gwih, gwhh, gbih, gbhh, X);
    }

    for (int it = 0; it < 3; ++it) {
        k_lstm<<<1, 256, 0, stream>>>(lwih, lwhh, lbih, lbhh, scal);
        k_escore<<<N / 4, 256, 0, stream>>>(X, scal, ev);
        k_max<<<1, 1024, 0, stream>>>(ev, scal, it);
        k_wread<<<64, 256, 0, stream>>>(X, ev, scal, it);
        k_fin<<<1, 128, 0, stream>>>(scal, (it == 2) ? outp : nullptr, it);
    }

    hipMemcpyAsync(outp + 128, X, (size_t)N * 64 * 4, hipMemcpyDeviceToDevice, stream);
}

// ---------------- bias contribution: agg[dst[e],o] += Σ_i x[e,i]*e2_b[i*64+o] ----------------
// 16 edges per block of 256; wave w: 4 edges; lane: sub=l>>4 edge, o4=(l&15)*4.
__global__ __launch_bounds__(256) void k_bias(const float* __restrict__ X,
        const float* __restrict__ e2b, const int* __restrict__ src,
        const int* __restrict__ dst, float* __restrict__ agg) {
    __shared__ float s[16][68];
    int tid = threadIdx.x;
    int e_base = blockIdx.x * 16;
    for (int v = tid; v < 16 * 64; v += 256) {
        int ee = e_base + (v >> 6);
        s[v >> 6][v & 63] = (ee < NE) ? X[(size_t)src[ee] * 64 + (v & 63)] : 0.f;
    }
    __syncthreads();
    int w = tid >> 6, l = tid & 63;
    int sub = l >> 4;
    int o4 = (l & 15) << 2;
    int e = e_base + w * 4 + sub;
    if (e >= NE) return;
    const float* sv = s[w * 4 + sub];
    float a0 = 0.f, a1 = 0.f, a2 = 0.f, a3 = 0.f;
    #pragma unroll 8
    for (int i = 0; i < 64; ++i) {
        float si = sv[i];
        const float* bp = &e2b[i * 64 + o4];
        a0 += si * bp[0];
        a1 += si * bp[1];
        a2 += si * bp[2];
        a3 += si * bp[3];
    }
    float* ap = &agg[(size_t)dst[e] * 64 + o4];
    atomicAdd(ap + 0, a0);
    atomicAdd(ap + 1, a1);
    atomicAdd(ap + 2, a2);
    atomicAdd(ap + 3, a3);
}